// Round 1
// 425.282 us; speedup vs baseline: 1.9544x; 1.9544x over previous
//
#include <hip/hip_runtime.h>

#define NN 10000
#define BB 32
#define EE 40000
#define HH 4
#define DD 10
#define TT 10
#define FS 12          // padded feat row stride (48 B, 16-B aligned)
#define NEG 0.2f

#define NB   (NN*BB)          // 320000
#define NBT  (NN*BB*TT)       // 3200000
#define NBF  (NN*BB*FS)       // 3840000 padded feat elems

// ---------------- extract mu/sigma + regression heads ----------------
__global__ void extract_kernel(const float* __restrict__ x,
                               const float* __restrict__ wmu, const float* __restrict__ bmu,
                               const float* __restrict__ wsg, const float* __restrict__ bsg,
                               float* __restrict__ mu, float* __restrict__ sg,
                               float* __restrict__ regmu, float* __restrict__ regsg) {
    int i = blockIdx.x * blockDim.x + threadIdx.x;   // over N*B
    if (i >= NB) return;
    int n = i / BB, b = i % BB;
    float smu = 0.f, ssg = 0.f;
    float muv[TT], sgv[TT];
#pragma unroll
    for (int t = 0; t < TT; t++) {
        size_t xi = (((size_t)t * NN + n) * BB + b) * 3;
        float m = x[xi], s = x[xi + 1];
        muv[t] = m; sgv[t] = s;
        smu += m * wmu[t];
        ssg += s * wsg[t];
    }
#pragma unroll
    for (int t = 0; t < TT; t++) {
        mu[(size_t)i * FS + t] = muv[t];
        sg[(size_t)i * FS + t] = sgv[t];
    }
    regmu[i] = smu + bmu[0];
    regsg[i] = ssg + bsg[0];
}

// ---------------- CSR build ----------------
__global__ void deg_kernel(const int* __restrict__ dst, int* __restrict__ deg) {
    int e = blockIdx.x * blockDim.x + threadIdx.x;
    if (e < EE) atomicAdd(&deg[dst[e]], 1);
}

// shfl-based scan: 40 barriers instead of 200
__global__ void scan_kernel(const int* __restrict__ deg, int* __restrict__ off) {
    __shared__ int sm[16];
    __shared__ int carry_s;
    int tid = threadIdx.x;               // 1024 threads = 16 waves
    int lane = tid & 63, wid = tid >> 6;
    if (tid == 0) { carry_s = 0; off[0] = 0; }
    __syncthreads();
    for (int base = 0; base < NN; base += 1024) {
        int i = base + tid;
        int v = (i < NN) ? deg[i] : 0;
        int x = v;
#pragma unroll
        for (int s = 1; s < 64; s <<= 1) {
            int t = __shfl_up(x, s, 64);
            if (lane >= s) x += t;
        }
        if (lane == 63) sm[wid] = x;
        __syncthreads();
        if (wid == 0) {
            int w = (lane < 16) ? sm[lane] : 0;
#pragma unroll
            for (int s = 1; s < 16; s <<= 1) {
                int t = __shfl_up(w, s, 64);
                if (lane >= s) w += t;
            }
            if (lane < 16) sm[lane] = w;
        }
        __syncthreads();
        int add = carry_s + ((wid > 0) ? sm[wid - 1] : 0);
        if (i < NN) off[i + 1] = add + x;
        int total = sm[15];
        __syncthreads();
        if (tid == 0) carry_s += total;
        __syncthreads();
    }
}

__global__ void fill_kernel(const int* __restrict__ src, const int* __restrict__ dst,
                            const int* __restrict__ off, int* __restrict__ cursor,
                            int* __restrict__ csr_src) {
    int e = blockIdx.x * blockDim.x + threadIdx.x;
    if (e < EE) {
        int d = dst[e];
        int p = atomicAdd(&cursor[d], 1);
        csr_src[off[d] + p] = src[e];
    }
}

// ---------------- precompute vl/vr for all 8 GATs ----------------
__global__ void vpre_kernel(const float* __restrict__ fc0, const float* __restrict__ al0, const float* __restrict__ ar0,
                            const float* __restrict__ fc1, const float* __restrict__ al1, const float* __restrict__ ar1,
                            const float* __restrict__ fc2, const float* __restrict__ al2, const float* __restrict__ ar2,
                            const float* __restrict__ fc3, const float* __restrict__ al3, const float* __restrict__ ar3,
                            float* __restrict__ vbuf) {
    int j = threadIdx.x;                 // 0..319
    if (j >= 320) return;
    int g = j / 40, r = j % 40;
    int h = r / 10, t = r % 10;
    int which = g & 3, layer = g >> 2;
    const float* fc; const float* al; const float* ar;
    if (which == 0)      { fc = fc0; al = al0; ar = ar0; }
    else if (which == 1) { fc = fc1; al = al1; ar = ar1; }
    else if (which == 2) { fc = fc2; al = al2; ar = ar2; }
    else                 { fc = fc3; al = al3; ar = ar3; }
    fc += layer * (HH * DD * TT);
    al += layer * (HH * DD);
    ar += layer * (HH * DD);
    float vl = 0.f, vr = 0.f;
#pragma unroll
    for (int d = 0; d < DD; d++) {
        float w = fc[(h * DD + d) * TT + t];
        vl += al[h * DD + d] * w;
        vr += ar[h * DD + d] * w;
    }
    vbuf[g * 80 + r] = vl;
    vbuf[g * 80 + 40 + r] = vr;
}

// ---------------- quad-GAT: thread = (n,b), ALL 4 HEADS in registers ------
// r7 theory: latency/MLP-bound. 4 head-lanes were re-loading identical rows;
// fold heads into one thread (4x fewer waves, 4x fewer load instrs, 4x more
// VALU per load), unroll edge loop x4 masked (12 row loads in flight),
// vl/vr via wave-uniform loads (SGPRs), W in LDS for epilogue only.
struct GatCfg {
    const float* f; const float* W; const float* v;
    const int* off; const int* csr;
    float* g; float* stats;
};
struct GatCfg4 { GatCfg c[4]; };

#define LOAD_ROW(dst, q)                                        \
    {                                                           \
        float4 _r0 = *(const float4*)(q);                       \
        float4 _r1 = *(const float4*)((q) + 4);                 \
        float2 _r2 = *(const float2*)((q) + 8);                 \
        dst[0]=_r0.x; dst[1]=_r0.y; dst[2]=_r0.z; dst[3]=_r0.w; \
        dst[4]=_r1.x; dst[5]=_r1.y; dst[6]=_r1.z; dst[7]=_r1.w; \
        dst[8]=_r2.x; dst[9]=_r2.y;                             \
    }

__device__ __forceinline__ void edge_accum(const float (&fa)[TT], bool val,
                                           const float* __restrict__ v,
                                           const float (&er)[HH],
                                           float (&den)[HH], float (&acc)[HH][TT]) {
#pragma unroll
    for (int h = 0; h < HH; h++) {
        float e = 0.f;
#pragma unroll
        for (int t = 0; t < TT; t++) e += v[h * TT + t] * fa[t];
        float z = e + er[h];
        z = (z >= 0.f) ? z : NEG * z;
        float w = val ? __expf(z) : 0.f;
        den[h] += w;
#pragma unroll
        for (int t = 0; t < TT; t++) acc[h][t] += w * fa[t];
    }
}

template <bool STATS>
__global__ void __launch_bounds__(256)
gat4_kernel(GatCfg4 cfgs) {
    const GatCfg cfg = cfgs.c[blockIdx.y];
    __shared__ __align__(16) float sW[HH * DD * 12];   // rows padded to 12 for float4 reads
    for (int kk = threadIdx.x; kk < HH * DD * TT; kk += blockDim.x) {
        int r = kk / TT, t = kk - r * TT;
        sW[r * 12 + t] = cfg.W[kk];
    }
    __syncthreads();

    const float* __restrict__ f   = cfg.f;
    const int*   __restrict__ csr = cfg.csr;
    const float* __restrict__ v   = cfg.v;   // wave-uniform: vl[40] | vr[40] -> SGPRs

    int i = blockIdx.x * blockDim.x + threadIdx.x;   // over NB
    float lsum = 0.f, lsq = 0.f;
    if (i < NB) {
        int b = i & 31;
        int n = i >> 5;
        int s0 = cfg.off[n], s1 = cfg.off[n + 1];

        // er_h from self features
        float er[HH];
        {
            float fs[TT];
            LOAD_ROW(fs, f + (size_t)i * FS);
#pragma unroll
            for (int h = 0; h < HH; h++) {
                float e = 0.f;
#pragma unroll
                for (int t = 0; t < TT; t++) e += v[HH * TT + h * TT + t] * fs[t];
                er[h] = e;
            }
        }

        float acc[HH][TT];
        float den[HH];
#pragma unroll
        for (int h = 0; h < HH; h++) {
            den[h] = 0.f;
#pragma unroll
            for (int t = 0; t < TT; t++) acc[h][t] = 0.f;
        }

        for (int k = s0; k < s1; k += 4) {
            const float* q0; const float* q1; const float* q2; const float* q3;
            {
                int k0 = k,     k1 = k + 1, k2 = k + 2, k3 = k + 3;
                int s_0 = csr[(k0 < s1) ? k0 : s0];
                int s_1 = csr[(k1 < s1) ? k1 : s0];
                int s_2 = csr[(k2 < s1) ? k2 : s0];
                int s_3 = csr[(k3 < s1) ? k3 : s0];
                q0 = f + (size_t)(s_0 * BB + b) * FS;
                q1 = f + (size_t)(s_1 * BB + b) * FS;
                q2 = f + (size_t)(s_2 * BB + b) * FS;
                q3 = f + (size_t)(s_3 * BB + b) * FS;
            }
            float fr0[TT], fr1[TT], fr2[TT], fr3[TT];
            LOAD_ROW(fr0, q0);
            LOAD_ROW(fr1, q1);
            LOAD_ROW(fr2, q2);
            LOAD_ROW(fr3, q3);
            edge_accum(fr0, (k     < s1), v, er, den, acc);
            edge_accum(fr1, (k + 1 < s1), v, er, den, acc);
            edge_accum(fr2, (k + 2 < s1), v, er, den, acc);
            edge_accum(fr3, (k + 3 < s1), v, er, den, acc);
        }

        float rd[HH];
#pragma unroll
        for (int h = 0; h < HH; h++) rd[h] = (s1 > s0) ? (1.0f / den[h]) : 0.f;

        // epilogue: W_h . acc_h, leaky, mean over heads (all in-thread now)
        float outv[DD];
#pragma unroll
        for (int d = 0; d < DD; d++) outv[d] = 0.f;
#pragma unroll
        for (int h = 0; h < HH; h++) {
#pragma unroll
            for (int d = 0; d < DD; d++) {
                const float* wr = &sW[(h * DD + d) * 12];
                float4 w0 = *(const float4*)wr;
                float4 w1 = *(const float4*)(wr + 4);
                float2 w2 = *(const float2*)(wr + 8);
                float va = w0.x * acc[h][0] + w0.y * acc[h][1] + w0.z * acc[h][2] + w0.w * acc[h][3]
                         + w1.x * acc[h][4] + w1.y * acc[h][5] + w1.z * acc[h][6] + w1.w * acc[h][7]
                         + w2.x * acc[h][8] + w2.y * acc[h][9];
                va *= rd[h];
                va = (va >= 0.f) ? va : NEG * va;
                outv[d] += va * 0.25f;
            }
        }

        float* gp = cfg.g + (size_t)i * DD;
#pragma unroll
        for (int d = 0; d < DD; d += 2) {
            *(float2*)(gp + d) = make_float2(outv[d], outv[d + 1]);
            if (STATS) {
                lsum += outv[d] + outv[d + 1];
                lsq  += outv[d] * outv[d] + outv[d + 1] * outv[d + 1];
            }
        }
    }
    if (STATS) {
#pragma unroll
        for (int o = 32; o > 0; o >>= 1) {
            lsum += __shfl_down(lsum, o, 64);
            lsq  += __shfl_down(lsq, o, 64);
        }
        __shared__ float ss[4][2];
        int wid = threadIdx.x >> 6, lid = threadIdx.x & 63;
        if (lid == 0) { ss[wid][0] = lsum; ss[wid][1] = lsq; }
        __syncthreads();
        if (threadIdx.x == 0) {
            float a0 = 0.f, a1 = 0.f;
#pragma unroll
            for (int w = 0; w < 4; w++) { a0 += ss[w][0]; a1 += ss[w][1]; }
            atomicAdd(&cfg.stats[0], a0);
            atomicAdd(&cfg.stats[1], a1);
        }
    }
}

// ---------------- LN(A), LN(B), average; writes padded feat rows ----------
__global__ void lncomb_kernel(const float* __restrict__ ga, const float* __restrict__ gb,
                              const float* __restrict__ stats, float* __restrict__ h) {
    int i = blockIdx.x * blockDim.x + threadIdx.x;
    if (i >= NBT) return;
    const float M = (float)NBT;
    float ma = stats[0] / M; float va = stats[1] / M - ma * ma;
    float mb = stats[2] / M; float vb = stats[3] / M - mb * mb;
    float ra = rsqrtf(va + 1e-5f), rb = rsqrtf(vb + 1e-5f);
    int nb = i / DD, t = i - nb * DD;
    h[(size_t)nb * FS + t] = 0.5f * ((ga[i] - ma) * ra + (gb[i] - mb) * rb);
}

// ---------------- final combine ----------------
__global__ void outcomb_kernel(const float* __restrict__ reg, const float* __restrict__ ga,
                               const float* __restrict__ gb, float* __restrict__ out) {
    int i = blockIdx.x * blockDim.x + threadIdx.x;
    if (i >= NBT) return;
    int nb = i / DD;
    out[i] = (reg[nb] + ga[i] + gb[i]) * (1.0f / 3.0f);
}

extern "C" void kernel_launch(void* const* d_in, const int* in_sizes, int n_in,
                              void* d_out, int out_size, void* d_ws, size_t ws_size,
                              hipStream_t stream) {
    const float* x      = (const float*)d_in[0];
    const int* ps_src   = (const int*)d_in[1];
    const int* ps_dst   = (const int*)d_in[2];
    const int* rl_src   = (const int*)d_in[3];
    const int* rl_dst   = (const int*)d_in[4];
    const float* mu_p_fc = (const float*)d_in[5];
    const float* mu_p_al = (const float*)d_in[6];
    const float* mu_p_ar = (const float*)d_in[7];
    const float* sg_p_fc = (const float*)d_in[8];
    const float* sg_p_al = (const float*)d_in[9];
    const float* sg_p_ar = (const float*)d_in[10];
    const float* mu_r_fc = (const float*)d_in[11];
    const float* mu_r_al = (const float*)d_in[12];
    const float* mu_r_ar = (const float*)d_in[13];
    const float* sg_r_fc = (const float*)d_in[14];
    const float* sg_r_al = (const float*)d_in[15];
    const float* sg_r_ar = (const float*)d_in[16];
    const float* reg_mu_w = (const float*)d_in[17];
    const float* reg_mu_b = (const float*)d_in[18];
    const float* reg_sg_w = (const float*)d_in[19];
    const float* reg_sg_b = (const float*)d_in[20];

    float* out = (float*)d_out;

    // ---- workspace carve ----
    float* fw = (float*)d_ws;
    float* mu    = fw;              fw += NBF;   // padded stride-12 feats
    float* sigma = fw;              fw += NBF;
    float* hp    = fw;              fw += NBF;
    float* hrl   = fw;              fw += NBF;
    float* gA    = fw;              fw += NBT;   // stride-10 GAT outputs
    float* gB    = fw;              fw += NBT;
    float* gA2   = fw;              fw += NBT;
    float* gB2   = fw;              fw += NBT;
    float* regmu = fw;              fw += NB;
    float* regsg = fw;              fw += NB;
    float* vbuf  = fw;              fw += 8 * 80;
    int* iw = (int*)fw;
    int* ps_off = iw;               iw += NN + 1;
    int* rl_off = iw;               iw += NN + 1;
    int* ps_csr = iw;               iw += EE;
    int* rl_csr = iw;               iw += EE;
    // zero region starts here:
    int* deg_ps = iw;               iw += NN;
    int* cur_ps = iw;               iw += NN;
    int* deg_rl = iw;               iw += NN;
    int* cur_rl = iw;               iw += NN;
    float* stats = (float*)iw;      // 8 floats
    size_t zero_bytes = (size_t)(4 * NN) * sizeof(int) + 8 * sizeof(float);
    hipMemsetAsync(deg_ps, 0, zero_bytes, stream);

    const int TPB = 256;
    const int GRID_NB  = (NB + TPB - 1) / TPB;
    const int GRID_NBT = (NBT + TPB - 1) / TPB;
    const int GRID_E   = (EE + TPB - 1) / TPB;
    const int GRID_GAT = 1256;   // ceil(NB/256)=1250, padded to %8==0 so cfg pairs share XCDs

    extract_kernel<<<GRID_NB, TPB, 0, stream>>>(x, reg_mu_w, reg_mu_b, reg_sg_w, reg_sg_b,
                                                mu, sigma, regmu, regsg);

    // CSR for both graphs
    deg_kernel<<<GRID_E, TPB, 0, stream>>>(ps_dst, deg_ps);
    deg_kernel<<<GRID_E, TPB, 0, stream>>>(rl_dst, deg_rl);
    scan_kernel<<<1, 1024, 0, stream>>>(deg_ps, ps_off);
    scan_kernel<<<1, 1024, 0, stream>>>(deg_rl, rl_off);
    fill_kernel<<<GRID_E, TPB, 0, stream>>>(ps_src, ps_dst, ps_off, cur_ps, ps_csr);
    fill_kernel<<<GRID_E, TPB, 0, stream>>>(rl_src, rl_dst, rl_off, cur_rl, rl_csr);

    // vl/vr precompute for all 8 GAT slots
    vpre_kernel<<<1, 320, 0, stream>>>(mu_p_fc, mu_p_al, mu_p_ar,
                                       sg_p_fc, sg_p_al, sg_p_ar,
                                       mu_r_fc, mu_r_al, mu_r_ar,
                                       sg_r_fc, sg_r_al, sg_r_ar, vbuf);

    // slots: 0 mu_p L0, 1 sg_p L0, 2 mu_r L0, 3 sg_r L0, 4 mu_p L1, 5 sg_p L1, 6 mu_r L1, 7 sg_r L1
    // ---- layer 0: 4 GATs in one dispatch ----
    {
        GatCfg4 c;
        c.c[0] = { mu,    mu_p_fc,       vbuf + 0 * 80, ps_off, ps_csr, gA,  stats + 0 };
        c.c[1] = { sigma, sg_p_fc,       vbuf + 1 * 80, ps_off, ps_csr, gB,  stats + 2 };
        c.c[2] = { mu,    mu_r_fc,       vbuf + 2 * 80, rl_off, rl_csr, gA2, stats + 4 };
        c.c[3] = { sigma, sg_r_fc,       vbuf + 3 * 80, rl_off, rl_csr, gB2, stats + 6 };
        dim3 grid(GRID_GAT, 4, 1);
        gat4_kernel<true><<<grid, TPB, 0, stream>>>(c);
    }
    lncomb_kernel<<<GRID_NBT, TPB, 0, stream>>>(gA, gB, stats + 0, hp);
    lncomb_kernel<<<GRID_NBT, TPB, 0, stream>>>(gA2, gB2, stats + 4, hrl);

    // ---- final layers: 4 GATs in one dispatch ----
    {
        GatCfg4 c;
        c.c[0] = { hp,  mu_p_fc + 400, vbuf + 4 * 80, ps_off, ps_csr, gA,  nullptr };
        c.c[1] = { hp,  sg_p_fc + 400, vbuf + 5 * 80, ps_off, ps_csr, gB,  nullptr };
        c.c[2] = { hrl, mu_r_fc + 400, vbuf + 6 * 80, rl_off, rl_csr, gA2, nullptr };
        c.c[3] = { hrl, sg_r_fc + 400, vbuf + 7 * 80, rl_off, rl_csr, gB2, nullptr };
        dim3 grid(GRID_GAT, 4, 1);
        gat4_kernel<false><<<grid, TPB, 0, stream>>>(c);
    }

    outcomb_kernel<<<GRID_NBT, TPB, 0, stream>>>(regmu, gA, gA2, out);
    outcomb_kernel<<<GRID_NBT, TPB, 0, stream>>>(regsg, gB, gB2, out + NBT);
}

// Round 2
// 420.417 us; speedup vs baseline: 1.9770x; 1.0116x over previous
//
#include <hip/hip_runtime.h>

#define NN 10000
#define BB 32
#define EE 40000
#define HH 4
#define DD 10
#define TT 10
#define FS 12          // padded feat row stride for single feats (48 B)
#define MS 24          // interleaved mu|sigma row stride (96 B)
#define NEG 0.2f

#define NB   (NN*BB)          // 320000
#define NBT  (NN*BB*TT)       // 3200000
#define NBF  (NN*BB*FS)       // 3840000 padded feat elems
#define NBM  (NN*BB*MS)       // 7680000 interleaved elems (== 2*NBF)

// ---------------- extract mu/sigma (interleaved) + regression heads -------
__global__ void extract_kernel(const float* __restrict__ x,
                               const float* __restrict__ wmu, const float* __restrict__ bmu,
                               const float* __restrict__ wsg, const float* __restrict__ bsg,
                               float* __restrict__ ms,
                               float* __restrict__ regmu, float* __restrict__ regsg) {
    int i = blockIdx.x * blockDim.x + threadIdx.x;   // over N*B
    if (i >= NB) return;
    int n = i / BB, b = i % BB;
    float smu = 0.f, ssg = 0.f;
    float muv[TT], sgv[TT];
#pragma unroll
    for (int t = 0; t < TT; t++) {
        size_t xi = (((size_t)t * NN + n) * BB + b) * 3;
        float m = x[xi], s = x[xi + 1];
        muv[t] = m; sgv[t] = s;
        smu += m * wmu[t];
        ssg += s * wsg[t];
    }
#pragma unroll
    for (int t = 0; t < TT; t++) {
        ms[(size_t)i * MS + t]      = muv[t];
        ms[(size_t)i * MS + 12 + t] = sgv[t];
    }
    regmu[i] = smu + bmu[0];
    regsg[i] = ssg + bsg[0];
}

// ---------------- CSR build (both graphs in one dispatch) ----------------
__global__ void deg2_kernel(const int* __restrict__ dst0, int* __restrict__ deg0,
                            const int* __restrict__ dst1, int* __restrict__ deg1) {
    int e = blockIdx.x * blockDim.x + threadIdx.x;
    const int* dst = blockIdx.y ? dst1 : dst0;
    int* deg       = blockIdx.y ? deg1 : deg0;
    if (e < EE) atomicAdd(&deg[dst[e]], 1);
}

// shfl-based scan; 2 blocks, one per graph
__global__ void scan2_kernel(const int* __restrict__ deg0, int* __restrict__ off0,
                             const int* __restrict__ deg1, int* __restrict__ off1) {
    const int* __restrict__ deg = blockIdx.x ? deg1 : deg0;
    int* __restrict__ off       = blockIdx.x ? off1 : off0;
    __shared__ int sm[16];
    __shared__ int carry_s;
    int tid = threadIdx.x;               // 1024 threads = 16 waves
    int lane = tid & 63, wid = tid >> 6;
    if (tid == 0) { carry_s = 0; off[0] = 0; }
    __syncthreads();
    for (int base = 0; base < NN; base += 1024) {
        int i = base + tid;
        int v = (i < NN) ? deg[i] : 0;
        int x = v;
#pragma unroll
        for (int s = 1; s < 64; s <<= 1) {
            int t = __shfl_up(x, s, 64);
            if (lane >= s) x += t;
        }
        if (lane == 63) sm[wid] = x;
        __syncthreads();
        if (wid == 0) {
            int w = (lane < 16) ? sm[lane] : 0;
#pragma unroll
            for (int s = 1; s < 16; s <<= 1) {
                int t = __shfl_up(w, s, 64);
                if (lane >= s) w += t;
            }
            if (lane < 16) sm[lane] = w;
        }
        __syncthreads();
        int add = carry_s + ((wid > 0) ? sm[wid - 1] : 0);
        if (i < NN) off[i + 1] = add + x;
        int total = sm[15];
        __syncthreads();
        if (tid == 0) carry_s += total;
        __syncthreads();
    }
}

__global__ void fill2_kernel(const int* __restrict__ src0, const int* __restrict__ dst0,
                             const int* __restrict__ off0, int* __restrict__ cur0,
                             int* __restrict__ csr0,
                             const int* __restrict__ src1, const int* __restrict__ dst1,
                             const int* __restrict__ off1, int* __restrict__ cur1,
                             int* __restrict__ csr1) {
    int e = blockIdx.x * blockDim.x + threadIdx.x;
    const int* src = blockIdx.y ? src1 : src0;
    const int* dst = blockIdx.y ? dst1 : dst0;
    const int* off = blockIdx.y ? off1 : off0;
    int* cursor    = blockIdx.y ? cur1 : cur0;
    int* csr       = blockIdx.y ? csr1 : csr0;
    if (e < EE) {
        int d = dst[e];
        int p = atomicAdd(&cursor[d], 1);
        csr[off[d] + p] = src[e];
    }
}

// ---------------- precompute vl/vr for all 8 GATs ----------------
__global__ void vpre_kernel(const float* __restrict__ fc0, const float* __restrict__ al0, const float* __restrict__ ar0,
                            const float* __restrict__ fc1, const float* __restrict__ al1, const float* __restrict__ ar1,
                            const float* __restrict__ fc2, const float* __restrict__ al2, const float* __restrict__ ar2,
                            const float* __restrict__ fc3, const float* __restrict__ al3, const float* __restrict__ ar3,
                            float* __restrict__ vbuf) {
    int j = threadIdx.x;                 // 0..319
    if (j >= 320) return;
    int g = j / 40, r = j % 40;
    int h = r / 10, t = r % 10;
    int which = g & 3, layer = g >> 2;
    const float* fc; const float* al; const float* ar;
    if (which == 0)      { fc = fc0; al = al0; ar = ar0; }
    else if (which == 1) { fc = fc1; al = al1; ar = ar1; }
    else if (which == 2) { fc = fc2; al = al2; ar = ar2; }
    else                 { fc = fc3; al = al3; ar = ar3; }
    fc += layer * (HH * DD * TT);
    al += layer * (HH * DD);
    ar += layer * (HH * DD);
    float vl = 0.f, vr = 0.f;
#pragma unroll
    for (int d = 0; d < DD; d++) {
        float w = fc[(h * DD + d) * TT + t];
        vl += al[h * DD + d] * w;
        vr += ar[h * DD + d] * w;
    }
    vbuf[g * 80 + r] = vl;
    vbuf[g * 80 + 40 + r] = vr;
}

// ---------------- pair-GAT: thread = (n,b), 2 GATs x 4 heads in regs ------
// r8 theory: still latency/MLP-bound (VALU 33%, HBM 14%). The two GATs of a
// pair share graph + feature rows: fold them into one thread. One loaded row
// now feeds 8 head-streams; L1 row loads halve; L0 rows interleaved (mu|sg)
// into one 96B record. Waves halve again, VALU per load doubles.
struct PairCfg {
    const float* f;                 // DUALF: stride 24 (A=+0, B=+12); else stride 12 shared
    const float* WA; const float* WB;
    const float* vA; const float* vB;
    const int* off; const int* csr;
    float* gA; float* gB;
    float* statsA; float* statsB;
};
struct PairCfg2 { PairCfg c[2]; };

#define LOAD_ROW(dst, q)                                        \
    {                                                           \
        float4 _r0 = *(const float4*)(q);                       \
        float4 _r1 = *(const float4*)((q) + 4);                 \
        float2 _r2 = *(const float2*)((q) + 8);                 \
        dst[0]=_r0.x; dst[1]=_r0.y; dst[2]=_r0.z; dst[3]=_r0.w; \
        dst[4]=_r1.x; dst[5]=_r1.y; dst[6]=_r1.z; dst[7]=_r1.w; \
        dst[8]=_r2.x; dst[9]=_r2.y;                             \
    }

__device__ __forceinline__ void eacc(const float (&fa)[TT], bool val,
                                     const float* __restrict__ v,
                                     const float (&er)[HH],
                                     float (&den)[HH], float (&acc)[HH][TT]) {
#pragma unroll
    for (int h = 0; h < HH; h++) {
        float e = 0.f;
#pragma unroll
        for (int t = 0; t < TT; t++) e += v[h * TT + t] * fa[t];
        float z = e + er[h];
        z = (z >= 0.f) ? z : NEG * z;
        float w = val ? __expf(z) : 0.f;
        den[h] += w;
#pragma unroll
        for (int t = 0; t < TT; t++) acc[h][t] += w * fa[t];
    }
}

template <bool DUALF, bool STATS>
__global__ void __launch_bounds__(256)
gatpair_kernel(PairCfg2 cfgs) {
    const PairCfg cfg = cfgs.c[blockIdx.y];
    __shared__ __align__(16) float sWA[HH * DD * 12];
    __shared__ __align__(16) float sWB[HH * DD * 12];
    for (int kk = threadIdx.x; kk < HH * DD * TT; kk += blockDim.x) {
        int r = kk / TT, t = kk - r * TT;
        sWA[r * 12 + t] = cfg.WA[kk];
        sWB[r * 12 + t] = cfg.WB[kk];
    }
    __syncthreads();

    const float* __restrict__ f   = cfg.f;
    const int*   __restrict__ csr = cfg.csr;
    const float* __restrict__ vA  = cfg.vA;  // wave-uniform -> SGPR loads
    const float* __restrict__ vB  = cfg.vB;
    const int LDR = DUALF ? MS : FS;

    int i = blockIdx.x * blockDim.x + threadIdx.x;   // over NB
    float lsA = 0.f, lqA = 0.f, lsB = 0.f, lqB = 0.f;
    if (i < NB) {
        int b = i & 31;
        int n = i >> 5;
        int s0 = cfg.off[n], s1 = cfg.off[n + 1];

        // er from self features, both GATs
        float erA[HH], erB[HH];
        {
            const float* p = f + (size_t)i * LDR;
            float fsA[TT];
            LOAD_ROW(fsA, p);
            float fsB[TT];
            if (DUALF) { LOAD_ROW(fsB, p + 12); }
#pragma unroll
            for (int h = 0; h < HH; h++) {
                float ea = 0.f, eb = 0.f;
#pragma unroll
                for (int t = 0; t < TT; t++) {
                    ea += vA[HH * TT + h * TT + t] * fsA[t];
                    eb += vB[HH * TT + h * TT + t] * (DUALF ? fsB[t] : fsA[t]);
                }
                erA[h] = ea; erB[h] = eb;
            }
        }

        float accA[HH][TT], accB[HH][TT];
        float denA[HH], denB[HH];
#pragma unroll
        for (int h = 0; h < HH; h++) {
            denA[h] = 0.f; denB[h] = 0.f;
#pragma unroll
            for (int t = 0; t < TT; t++) { accA[h][t] = 0.f; accB[h][t] = 0.f; }
        }

        for (int k = s0; k < s1; k += 2) {
            int k1 = (k + 1 < s1) ? k + 1 : k;
            bool v1 = (k + 1 < s1);
            int e0 = csr[k], e1 = csr[k1];
            const float* q0 = f + (size_t)(e0 * BB + b) * LDR;
            const float* q1 = f + (size_t)(e1 * BB + b) * LDR;
            float a0[TT], a1[TT];
            LOAD_ROW(a0, q0);
            LOAD_ROW(a1, q1);
            if (DUALF) {
                float b0[TT], b1[TT];
                LOAD_ROW(b0, q0 + 12);
                LOAD_ROW(b1, q1 + 12);
                eacc(a0, true, vA, erA, denA, accA);
                eacc(b0, true, vB, erB, denB, accB);
                eacc(a1, v1,   vA, erA, denA, accA);
                eacc(b1, v1,   vB, erB, denB, accB);
            } else {
                eacc(a0, true, vA, erA, denA, accA);
                eacc(a0, true, vB, erB, denB, accB);
                eacc(a1, v1,   vA, erA, denA, accA);
                eacc(a1, v1,   vB, erB, denB, accB);
            }
        }

        bool nz = (s1 > s0);
        float* gpA = cfg.gA + (size_t)i * DD;
        float* gpB = cfg.gB + (size_t)i * DD;

        // epilogue GAT A then GAT B (outv regs reused)
#pragma unroll
        for (int g = 0; g < 2; g++) {
            const float (*acc)[TT] = g ? accB : accA;
            const float* den = g ? denB : denA;
            const float* sW  = g ? sWB : sWA;
            float* gp        = g ? gpB : gpA;
            float rd[HH];
#pragma unroll
            for (int h = 0; h < HH; h++) rd[h] = nz ? (1.0f / den[h]) : 0.f;
            float outv[DD];
#pragma unroll
            for (int d = 0; d < DD; d++) outv[d] = 0.f;
#pragma unroll
            for (int h = 0; h < HH; h++) {
#pragma unroll
                for (int d = 0; d < DD; d++) {
                    const float* wr = &sW[(h * DD + d) * 12];
                    float4 w0 = *(const float4*)wr;
                    float4 w1 = *(const float4*)(wr + 4);
                    float2 w2 = *(const float2*)(wr + 8);
                    float va = w0.x * acc[h][0] + w0.y * acc[h][1] + w0.z * acc[h][2] + w0.w * acc[h][3]
                             + w1.x * acc[h][4] + w1.y * acc[h][5] + w1.z * acc[h][6] + w1.w * acc[h][7]
                             + w2.x * acc[h][8] + w2.y * acc[h][9];
                    va *= rd[h];
                    va = (va >= 0.f) ? va : NEG * va;
                    outv[d] += va * 0.25f;
                }
            }
#pragma unroll
            for (int d = 0; d < DD; d += 2)
                *(float2*)(gp + d) = make_float2(outv[d], outv[d + 1]);
            if (STATS) {
                float s = 0.f, q = 0.f;
#pragma unroll
                for (int d = 0; d < DD; d++) { s += outv[d]; q += outv[d] * outv[d]; }
                if (g) { lsB = s; lqB = q; } else { lsA = s; lqA = q; }
            }
        }
    }
    if (STATS) {
#pragma unroll
        for (int o = 32; o > 0; o >>= 1) {
            lsA += __shfl_down(lsA, o, 64);
            lqA += __shfl_down(lqA, o, 64);
            lsB += __shfl_down(lsB, o, 64);
            lqB += __shfl_down(lqB, o, 64);
        }
        __shared__ float ss[4][4];
        int wid = threadIdx.x >> 6, lid = threadIdx.x & 63;
        if (lid == 0) { ss[wid][0] = lsA; ss[wid][1] = lqA; ss[wid][2] = lsB; ss[wid][3] = lqB; }
        __syncthreads();
        if (threadIdx.x == 0) {
            float a0 = 0.f, a1 = 0.f, a2 = 0.f, a3 = 0.f;
#pragma unroll
            for (int w = 0; w < 4; w++) { a0 += ss[w][0]; a1 += ss[w][1]; a2 += ss[w][2]; a3 += ss[w][3]; }
            atomicAdd(&cfg.statsA[0], a0);
            atomicAdd(&cfg.statsA[1], a1);
            atomicAdd(&cfg.statsB[0], a2);
            atomicAdd(&cfg.statsB[1], a3);
        }
    }
}

// ---------------- LN(A), LN(B), average; both graphs in one dispatch ------
__global__ void lncomb2_kernel(const float* __restrict__ gA, const float* __restrict__ gB,
                               const float* __restrict__ gA2, const float* __restrict__ gB2,
                               const float* __restrict__ stats,
                               float* __restrict__ hp, float* __restrict__ hrl) {
    int i = blockIdx.x * blockDim.x + threadIdx.x;
    if (i >= NBT) return;
    const float* ga = blockIdx.y ? gA2 : gA;
    const float* gb = blockIdx.y ? gB2 : gB;
    const float* st = stats + (blockIdx.y ? 4 : 0);
    float* h        = blockIdx.y ? hrl : hp;
    const float M = (float)NBT;
    float ma = st[0] / M; float va = st[1] / M - ma * ma;
    float mb = st[2] / M; float vb = st[3] / M - mb * mb;
    float ra = rsqrtf(va + 1e-5f), rb = rsqrtf(vb + 1e-5f);
    int nb = i / DD, t = i - nb * DD;
    h[(size_t)nb * FS + t] = 0.5f * ((ga[i] - ma) * ra + (gb[i] - mb) * rb);
}

// ---------------- final combine, both outputs in one dispatch -------------
__global__ void outcomb2_kernel(const float* __restrict__ regmu, const float* __restrict__ regsg,
                                const float* __restrict__ gA, const float* __restrict__ gA2,
                                const float* __restrict__ gB, const float* __restrict__ gB2,
                                float* __restrict__ out) {
    int i = blockIdx.x * blockDim.x + threadIdx.x;
    if (i >= NBT) return;
    int nb = i / DD;
    if (blockIdx.y == 0) out[i]       = (regmu[nb] + gA[i] + gA2[i]) * (1.0f / 3.0f);
    else                 out[NBT + i] = (regsg[nb] + gB[i] + gB2[i]) * (1.0f / 3.0f);
}

extern "C" void kernel_launch(void* const* d_in, const int* in_sizes, int n_in,
                              void* d_out, int out_size, void* d_ws, size_t ws_size,
                              hipStream_t stream) {
    const float* x      = (const float*)d_in[0];
    const int* ps_src   = (const int*)d_in[1];
    const int* ps_dst   = (const int*)d_in[2];
    const int* rl_src   = (const int*)d_in[3];
    const int* rl_dst   = (const int*)d_in[4];
    const float* mu_p_fc = (const float*)d_in[5];
    const float* mu_p_al = (const float*)d_in[6];
    const float* mu_p_ar = (const float*)d_in[7];
    const float* sg_p_fc = (const float*)d_in[8];
    const float* sg_p_al = (const float*)d_in[9];
    const float* sg_p_ar = (const float*)d_in[10];
    const float* mu_r_fc = (const float*)d_in[11];
    const float* mu_r_al = (const float*)d_in[12];
    const float* mu_r_ar = (const float*)d_in[13];
    const float* sg_r_fc = (const float*)d_in[14];
    const float* sg_r_al = (const float*)d_in[15];
    const float* sg_r_ar = (const float*)d_in[16];
    const float* reg_mu_w = (const float*)d_in[17];
    const float* reg_mu_b = (const float*)d_in[18];
    const float* reg_sg_w = (const float*)d_in[19];
    const float* reg_sg_b = (const float*)d_in[20];

    float* out = (float*)d_out;

    // ---- workspace carve ----
    float* fw = (float*)d_ws;
    float* ms    = fw;              fw += NBM;   // interleaved mu|sigma, stride 24
    float* hp    = fw;              fw += NBF;   // stride-12 feats
    float* hrl   = fw;              fw += NBF;
    float* gA    = fw;              fw += NBT;   // stride-10 GAT outputs
    float* gB    = fw;              fw += NBT;
    float* gA2   = fw;              fw += NBT;
    float* gB2   = fw;              fw += NBT;
    float* regmu = fw;              fw += NB;
    float* regsg = fw;              fw += NB;
    float* vbuf  = fw;              fw += 8 * 80;
    int* iw = (int*)fw;
    int* ps_off = iw;               iw += NN + 1;
    int* rl_off = iw;               iw += NN + 1;
    int* ps_csr = iw;               iw += EE;
    int* rl_csr = iw;               iw += EE;
    // zero region starts here:
    int* deg_ps = iw;               iw += NN;
    int* cur_ps = iw;               iw += NN;
    int* deg_rl = iw;               iw += NN;
    int* cur_rl = iw;               iw += NN;
    float* stats = (float*)iw;      // 8 floats
    size_t zero_bytes = (size_t)(4 * NN) * sizeof(int) + 8 * sizeof(float);
    hipMemsetAsync(deg_ps, 0, zero_bytes, stream);

    const int TPB = 256;
    const int GRID_NB  = (NB + TPB - 1) / TPB;      // 1250
    const int GRID_NBT = (NBT + TPB - 1) / TPB;
    const int GRID_E   = (EE + TPB - 1) / TPB;

    extract_kernel<<<GRID_NB, TPB, 0, stream>>>(x, reg_mu_w, reg_mu_b, reg_sg_w, reg_sg_b,
                                                ms, regmu, regsg);

    // CSR for both graphs (fused dispatches)
    {
        dim3 g(GRID_E, 2, 1);
        deg2_kernel<<<g, TPB, 0, stream>>>(ps_dst, deg_ps, rl_dst, deg_rl);
        scan2_kernel<<<2, 1024, 0, stream>>>(deg_ps, ps_off, deg_rl, rl_off);
        fill2_kernel<<<g, TPB, 0, stream>>>(ps_src, ps_dst, ps_off, cur_ps, ps_csr,
                                            rl_src, rl_dst, rl_off, cur_rl, rl_csr);
    }

    // vl/vr precompute for all 8 GAT slots
    vpre_kernel<<<1, 320, 0, stream>>>(mu_p_fc, mu_p_al, mu_p_ar,
                                       sg_p_fc, sg_p_al, sg_p_ar,
                                       mu_r_fc, mu_r_al, mu_r_ar,
                                       sg_r_fc, sg_r_al, sg_r_ar, vbuf);

    // slots: 0 mu_p L0, 1 sg_p L0, 2 mu_r L0, 3 sg_r L0, 4 mu_p L1, 5 sg_p L1, 6 mu_r L1, 7 sg_r L1
    // ---- layer 0: 2 pairs (ps: mu_p+sg_p, rl: mu_r+sg_r) on interleaved ms ----
    {
        PairCfg2 c;
        c.c[0] = { ms, mu_p_fc, sg_p_fc, vbuf + 0 * 80, vbuf + 1 * 80,
                   ps_off, ps_csr, gA,  gB,  stats + 0, stats + 2 };
        c.c[1] = { ms, mu_r_fc, sg_r_fc, vbuf + 2 * 80, vbuf + 3 * 80,
                   rl_off, rl_csr, gA2, gB2, stats + 4, stats + 6 };
        dim3 grid(GRID_NB, 2, 1);
        gatpair_kernel<true, true><<<grid, TPB, 0, stream>>>(c);
    }
    {
        dim3 g(GRID_NBT, 2, 1);
        lncomb2_kernel<<<g, TPB, 0, stream>>>(gA, gB, gA2, gB2, stats, hp, hrl);
    }

    // ---- final layers: 2 pairs, shared feature row per pair ----
    {
        PairCfg2 c;
        c.c[0] = { hp,  mu_p_fc + 400, sg_p_fc + 400, vbuf + 4 * 80, vbuf + 5 * 80,
                   ps_off, ps_csr, gA,  gB,  nullptr, nullptr };
        c.c[1] = { hrl, mu_r_fc + 400, sg_r_fc + 400, vbuf + 6 * 80, vbuf + 7 * 80,
                   rl_off, rl_csr, gA2, gB2, nullptr, nullptr };
        dim3 grid(GRID_NB, 2, 1);
        gatpair_kernel<false, false><<<grid, TPB, 0, stream>>>(c);
    }

    {
        dim3 g(GRID_NBT, 2, 1);
        outcomb2_kernel<<<g, TPB, 0, stream>>>(regmu, regsg, gA, gA2, gB, gB2, out);
    }
}

// Round 4
// 413.157 us; speedup vs baseline: 2.0117x; 1.0176x over previous
//
#include <hip/hip_runtime.h>

// r10: resubmit of r9 (degree-sort experiment) — r9 bench died at container
// acquisition (infra), no on-GPU verdict was produced. Source unchanged.

#define NN 10000
#define BB 32
#define EE 40000
#define HH 4
#define DD 10
#define TT 10
#define FS 12          // padded feat row stride for single feats (48 B)
#define MS 24          // interleaved mu|sigma row stride (96 B)
#define NEG 0.2f

#define NB   (NN*BB)          // 320000
#define NBT  (NN*BB*TT)       // 3200000
#define NBF  (NN*BB*FS)       // 3840000 padded feat elems
#define NBM  (NN*BB*MS)       // 7680000 interleaved elems (== 2*NBF)

// ---------------- extract mu/sigma (interleaved) + regression heads -------
__global__ void extract_kernel(const float* __restrict__ x,
                               const float* __restrict__ wmu, const float* __restrict__ bmu,
                               const float* __restrict__ wsg, const float* __restrict__ bsg,
                               float* __restrict__ ms,
                               float* __restrict__ regmu, float* __restrict__ regsg) {
    int i = blockIdx.x * blockDim.x + threadIdx.x;   // over N*B
    if (i >= NB) return;
    int n = i / BB, b = i % BB;
    float smu = 0.f, ssg = 0.f;
    float muv[TT], sgv[TT];
#pragma unroll
    for (int t = 0; t < TT; t++) {
        size_t xi = (((size_t)t * NN + n) * BB + b) * 3;
        float m = x[xi], s = x[xi + 1];
        muv[t] = m; sgv[t] = s;
        smu += m * wmu[t];
        ssg += s * wsg[t];
    }
#pragma unroll
    for (int t = 0; t < TT; t++) {
        ms[(size_t)i * MS + t]      = muv[t];
        ms[(size_t)i * MS + 12 + t] = sgv[t];
    }
    regmu[i] = smu + bmu[0];
    regsg[i] = ssg + bsg[0];
}

// ---------------- CSR build (both graphs in one dispatch) ----------------
__global__ void deg2_kernel(const int* __restrict__ dst0, int* __restrict__ deg0,
                            const int* __restrict__ dst1, int* __restrict__ deg1) {
    int e = blockIdx.x * blockDim.x + threadIdx.x;
    const int* dst = blockIdx.y ? dst1 : dst0;
    int* deg       = blockIdx.y ? deg1 : deg0;
    if (e < EE) atomicAdd(&deg[dst[e]], 1);
}

// shfl-based scan; 2 blocks, one per graph
__global__ void scan2_kernel(const int* __restrict__ deg0, int* __restrict__ off0,
                             const int* __restrict__ deg1, int* __restrict__ off1) {
    const int* __restrict__ deg = blockIdx.x ? deg1 : deg0;
    int* __restrict__ off       = blockIdx.x ? off1 : off0;
    __shared__ int sm[16];
    __shared__ int carry_s;
    int tid = threadIdx.x;               // 1024 threads = 16 waves
    int lane = tid & 63, wid = tid >> 6;
    if (tid == 0) { carry_s = 0; off[0] = 0; }
    __syncthreads();
    for (int base = 0; base < NN; base += 1024) {
        int i = base + tid;
        int v = (i < NN) ? deg[i] : 0;
        int x = v;
#pragma unroll
        for (int s = 1; s < 64; s <<= 1) {
            int t = __shfl_up(x, s, 64);
            if (lane >= s) x += t;
        }
        if (lane == 63) sm[wid] = x;
        __syncthreads();
        if (wid == 0) {
            int w = (lane < 16) ? sm[lane] : 0;
#pragma unroll
            for (int s = 1; s < 16; s <<= 1) {
                int t = __shfl_up(w, s, 64);
                if (lane >= s) w += t;
            }
            if (lane < 16) sm[lane] = w;
        }
        __syncthreads();
        int add = carry_s + ((wid > 0) ? sm[wid - 1] : 0);
        if (i < NN) off[i + 1] = add + x;
        int total = sm[15];
        __syncthreads();
        if (tid == 0) carry_s += total;
        __syncthreads();
    }
}

__global__ void fill2_kernel(const int* __restrict__ src0, const int* __restrict__ dst0,
                             const int* __restrict__ off0, int* __restrict__ cur0,
                             int* __restrict__ csr0,
                             const int* __restrict__ src1, const int* __restrict__ dst1,
                             const int* __restrict__ off1, int* __restrict__ cur1,
                             int* __restrict__ csr1) {
    int e = blockIdx.x * blockDim.x + threadIdx.x;
    const int* src = blockIdx.y ? src1 : src0;
    const int* dst = blockIdx.y ? dst1 : dst0;
    const int* off = blockIdx.y ? off1 : off0;
    int* cursor    = blockIdx.y ? cur1 : cur0;
    int* csr       = blockIdx.y ? csr1 : csr0;
    if (e < EE) {
        int d = dst[e];
        int p = atomicAdd(&cursor[d], 1);
        csr[off[d] + p] = src[e];
    }
}

// ---------------- degree sort: counting sort into perm (descending deg) ---
// bin = 63 - min(deg,63); ascending bin order == descending degree.
__global__ void hist2_kernel(const int* __restrict__ deg0, const int* __restrict__ deg1,
                             int* __restrict__ hist) {
    __shared__ int lh[64];
    if (threadIdx.x < 64) lh[threadIdx.x] = 0;
    __syncthreads();
    int n = blockIdx.x * blockDim.x + threadIdx.x;
    int g = blockIdx.y;
    const int* deg = g ? deg1 : deg0;
    if (n < NN) {
        int d = deg[n];
        int bin = 63 - ((d < 63) ? d : 63);
        atomicAdd(&lh[bin], 1);
    }
    __syncthreads();
    if (threadIdx.x < 64 && lh[threadIdx.x])
        atomicAdd(&hist[g * 64 + threadIdx.x], lh[threadIdx.x]);
}

__global__ void binoff_kernel(const int* __restrict__ hist, int* __restrict__ boff) {
    // 128 threads: 2 waves, each does an exclusive scan of its graph's 64 bins
    int g = threadIdx.x >> 6, lane = threadIdx.x & 63;
    int v = hist[g * 64 + lane];
    int x = v;
#pragma unroll
    for (int s = 1; s < 64; s <<= 1) {
        int t = __shfl_up(x, s, 64);
        if (lane >= s) x += t;
    }
    boff[g * 64 + lane] = x - v;
}

__global__ void permfill2_kernel(const int* __restrict__ deg0, const int* __restrict__ deg1,
                                 const int* __restrict__ boff, int* __restrict__ bcur,
                                 int* __restrict__ perm0, int* __restrict__ perm1) {
    __shared__ int lh[64], lbase[64];
    if (threadIdx.x < 64) lh[threadIdx.x] = 0;
    __syncthreads();
    int n = blockIdx.x * blockDim.x + threadIdx.x;
    int g = blockIdx.y;
    const int* deg = g ? deg1 : deg0;
    int* perm      = g ? perm1 : perm0;
    int bin = 0, myp = 0;
    if (n < NN) {
        int d = deg[n];
        bin = 63 - ((d < 63) ? d : 63);
        myp = atomicAdd(&lh[bin], 1);
    }
    __syncthreads();
    if (threadIdx.x < 64) {
        int c = lh[threadIdx.x];
        lbase[threadIdx.x] = c ? atomicAdd(&bcur[g * 64 + threadIdx.x], c) : 0;
    }
    __syncthreads();
    if (n < NN) perm[boff[g * 64 + bin] + lbase[bin] + myp] = n;
}

// ---------------- precompute vl/vr for all 8 GATs ----------------
__global__ void vpre_kernel(const float* __restrict__ fc0, const float* __restrict__ al0, const float* __restrict__ ar0,
                            const float* __restrict__ fc1, const float* __restrict__ al1, const float* __restrict__ ar1,
                            const float* __restrict__ fc2, const float* __restrict__ al2, const float* __restrict__ ar2,
                            const float* __restrict__ fc3, const float* __restrict__ al3, const float* __restrict__ ar3,
                            float* __restrict__ vbuf) {
    int j = threadIdx.x;                 // 0..319
    if (j >= 320) return;
    int g = j / 40, r = j % 40;
    int h = r / 10, t = r % 10;
    int which = g & 3, layer = g >> 2;
    const float* fc; const float* al; const float* ar;
    if (which == 0)      { fc = fc0; al = al0; ar = ar0; }
    else if (which == 1) { fc = fc1; al = al1; ar = ar1; }
    else if (which == 2) { fc = fc2; al = al2; ar = ar2; }
    else                 { fc = fc3; al = al3; ar = ar3; }
    fc += layer * (HH * DD * TT);
    al += layer * (HH * DD);
    ar += layer * (HH * DD);
    float vl = 0.f, vr = 0.f;
#pragma unroll
    for (int d = 0; d < DD; d++) {
        float w = fc[(h * DD + d) * TT + t];
        vl += al[h * DD + d] * w;
        vr += ar[h * DD + d] * w;
    }
    vbuf[g * 80 + r] = vl;
    vbuf[g * 80 + 40 + r] = vr;
}

// ---------------- pair-GAT with degree-sorted node assignment -------------
// theory: time tracks wave-issued iterations (max deg over the wave's 2
// nodes, ~33% dud work with random assignment). Sorted permutation makes the
// wave's nodes equal-degree -> trip == own deg, duds ~gone, long nodes start
// first. Edge order per node unchanged -> bitwise-identical sums.
struct PairCfg {
    const float* f;                 // DUALF: stride 24 (A=+0, B=+12); else stride 12 shared
    const float* WA; const float* WB;
    const float* vA; const float* vB;
    const int* off; const int* csr; const int* perm;
    float* gA; float* gB;
    float* statsA; float* statsB;
};
struct PairCfg2 { PairCfg c[2]; };

#define LOAD_ROW(dst, q)                                        \
    {                                                           \
        float4 _r0 = *(const float4*)(q);                       \
        float4 _r1 = *(const float4*)((q) + 4);                 \
        float2 _r2 = *(const float2*)((q) + 8);                 \
        dst[0]=_r0.x; dst[1]=_r0.y; dst[2]=_r0.z; dst[3]=_r0.w; \
        dst[4]=_r1.x; dst[5]=_r1.y; dst[6]=_r1.z; dst[7]=_r1.w; \
        dst[8]=_r2.x; dst[9]=_r2.y;                             \
    }

__device__ __forceinline__ void eacc(const float (&fa)[TT], bool val,
                                     const float* __restrict__ v,
                                     const float (&er)[HH],
                                     float (&den)[HH], float (&acc)[HH][TT]) {
#pragma unroll
    for (int h = 0; h < HH; h++) {
        float e = 0.f;
#pragma unroll
        for (int t = 0; t < TT; t++) e += v[h * TT + t] * fa[t];
        float z = e + er[h];
        z = (z >= 0.f) ? z : NEG * z;
        float w = val ? __expf(z) : 0.f;
        den[h] += w;
#pragma unroll
        for (int t = 0; t < TT; t++) acc[h][t] += w * fa[t];
    }
}

template <bool DUALF, bool STATS>
__global__ void __launch_bounds__(256)
gatpair_kernel(PairCfg2 cfgs) {
    const PairCfg cfg = cfgs.c[blockIdx.y];
    __shared__ __align__(16) float sWA[HH * DD * 12];
    __shared__ __align__(16) float sWB[HH * DD * 12];
    for (int kk = threadIdx.x; kk < HH * DD * TT; kk += blockDim.x) {
        int r = kk / TT, t = kk - r * TT;
        sWA[r * 12 + t] = cfg.WA[kk];
        sWB[r * 12 + t] = cfg.WB[kk];
    }
    __syncthreads();

    const float* __restrict__ f   = cfg.f;
    const int*   __restrict__ csr = cfg.csr;
    const float* __restrict__ vA  = cfg.vA;  // wave-uniform -> SGPR loads
    const float* __restrict__ vB  = cfg.vB;
    const int LDR = DUALF ? MS : FS;

    int i = blockIdx.x * blockDim.x + threadIdx.x;   // over NB (sorted slots)
    float lsA = 0.f, lqA = 0.f, lsB = 0.f, lqB = 0.f;
    if (i < NB) {
        int b = i & 31;
        int slot = i >> 5;
        int n = cfg.perm[slot];          // degree-sorted node id
        int nb = n * BB + b;
        int s0 = cfg.off[n], s1 = cfg.off[n + 1];

        // er from self features, both GATs
        float erA[HH], erB[HH];
        {
            const float* p = f + (size_t)nb * LDR;
            float fsA[TT];
            LOAD_ROW(fsA, p);
            float fsB[TT];
            if (DUALF) { LOAD_ROW(fsB, p + 12); }
#pragma unroll
            for (int h = 0; h < HH; h++) {
                float ea = 0.f, eb = 0.f;
#pragma unroll
                for (int t = 0; t < TT; t++) {
                    ea += vA[HH * TT + h * TT + t] * fsA[t];
                    eb += vB[HH * TT + h * TT + t] * (DUALF ? fsB[t] : fsA[t]);
                }
                erA[h] = ea; erB[h] = eb;
            }
        }

        float accA[HH][TT], accB[HH][TT];
        float denA[HH], denB[HH];
#pragma unroll
        for (int h = 0; h < HH; h++) {
            denA[h] = 0.f; denB[h] = 0.f;
#pragma unroll
            for (int t = 0; t < TT; t++) { accA[h][t] = 0.f; accB[h][t] = 0.f; }
        }

        for (int k = s0; k < s1; k += 2) {
            int k1 = (k + 1 < s1) ? k + 1 : k;
            bool v1 = (k + 1 < s1);
            int e0 = csr[k], e1 = csr[k1];
            const float* q0 = f + (size_t)(e0 * BB + b) * LDR;
            const float* q1 = f + (size_t)(e1 * BB + b) * LDR;
            float a0[TT], a1[TT];
            LOAD_ROW(a0, q0);
            LOAD_ROW(a1, q1);
            if (DUALF) {
                float b0[TT], b1[TT];
                LOAD_ROW(b0, q0 + 12);
                LOAD_ROW(b1, q1 + 12);
                eacc(a0, true, vA, erA, denA, accA);
                eacc(b0, true, vB, erB, denB, accB);
                eacc(a1, v1,   vA, erA, denA, accA);
                eacc(b1, v1,   vB, erB, denB, accB);
            } else {
                eacc(a0, true, vA, erA, denA, accA);
                eacc(a0, true, vB, erB, denB, accB);
                eacc(a1, v1,   vA, erA, denA, accA);
                eacc(a1, v1,   vB, erB, denB, accB);
            }
        }

        bool nz = (s1 > s0);
        float* gpA = cfg.gA + (size_t)nb * DD;
        float* gpB = cfg.gB + (size_t)nb * DD;

        // epilogue GAT A then GAT B (outv regs reused)
#pragma unroll
        for (int g = 0; g < 2; g++) {
            const float (*acc)[TT] = g ? accB : accA;
            const float* den = g ? denB : denA;
            const float* sW  = g ? sWB : sWA;
            float* gp        = g ? gpB : gpA;
            float rd[HH];
#pragma unroll
            for (int h = 0; h < HH; h++) rd[h] = nz ? (1.0f / den[h]) : 0.f;
            float outv[DD];
#pragma unroll
            for (int d = 0; d < DD; d++) outv[d] = 0.f;
#pragma unroll
            for (int h = 0; h < HH; h++) {
#pragma unroll
                for (int d = 0; d < DD; d++) {
                    const float* wr = &sW[(h * DD + d) * 12];
                    float4 w0 = *(const float4*)wr;
                    float4 w1 = *(const float4*)(wr + 4);
                    float2 w2 = *(const float2*)(wr + 8);
                    float va = w0.x * acc[h][0] + w0.y * acc[h][1] + w0.z * acc[h][2] + w0.w * acc[h][3]
                             + w1.x * acc[h][4] + w1.y * acc[h][5] + w1.z * acc[h][6] + w1.w * acc[h][7]
                             + w2.x * acc[h][8] + w2.y * acc[h][9];
                    va *= rd[h];
                    va = (va >= 0.f) ? va : NEG * va;
                    outv[d] += va * 0.25f;
                }
            }
#pragma unroll
            for (int d = 0; d < DD; d += 2)
                *(float2*)(gp + d) = make_float2(outv[d], outv[d + 1]);
            if (STATS) {
                float s = 0.f, q = 0.f;
#pragma unroll
                for (int d = 0; d < DD; d++) { s += outv[d]; q += outv[d] * outv[d]; }
                if (g) { lsB = s; lqB = q; } else { lsA = s; lqA = q; }
            }
        }
    }
    if (STATS) {
#pragma unroll
        for (int o = 32; o > 0; o >>= 1) {
            lsA += __shfl_down(lsA, o, 64);
            lqA += __shfl_down(lqA, o, 64);
            lsB += __shfl_down(lsB, o, 64);
            lqB += __shfl_down(lqB, o, 64);
        }
        __shared__ float ss[4][4];
        int wid = threadIdx.x >> 6, lid = threadIdx.x & 63;
        if (lid == 0) { ss[wid][0] = lsA; ss[wid][1] = lqA; ss[wid][2] = lsB; ss[wid][3] = lqB; }
        __syncthreads();
        if (threadIdx.x == 0) {
            float a0 = 0.f, a1 = 0.f, a2 = 0.f, a3 = 0.f;
#pragma unroll
            for (int w = 0; w < 4; w++) { a0 += ss[w][0]; a1 += ss[w][1]; a2 += ss[w][2]; a3 += ss[w][3]; }
            atomicAdd(&cfg.statsA[0], a0);
            atomicAdd(&cfg.statsA[1], a1);
            atomicAdd(&cfg.statsB[0], a2);
            atomicAdd(&cfg.statsB[1], a3);
        }
    }
}

// ---------------- LN(A), LN(B), average; both graphs in one dispatch ------
__global__ void lncomb2_kernel(const float* __restrict__ gA, const float* __restrict__ gB,
                               const float* __restrict__ gA2, const float* __restrict__ gB2,
                               const float* __restrict__ stats,
                               float* __restrict__ hp, float* __restrict__ hrl) {
    int i = blockIdx.x * blockDim.x + threadIdx.x;
    if (i >= NBT) return;
    const float* ga = blockIdx.y ? gA2 : gA;
    const float* gb = blockIdx.y ? gB2 : gB;
    const float* st = stats + (blockIdx.y ? 4 : 0);
    float* h        = blockIdx.y ? hrl : hp;
    const float M = (float)NBT;
    float ma = st[0] / M; float va = st[1] / M - ma * ma;
    float mb = st[2] / M; float vb = st[3] / M - mb * mb;
    float ra = rsqrtf(va + 1e-5f), rb = rsqrtf(vb + 1e-5f);
    int nb = i / DD, t = i - nb * DD;
    h[(size_t)nb * FS + t] = 0.5f * ((ga[i] - ma) * ra + (gb[i] - mb) * rb);
}

// ---------------- final combine, both outputs in one dispatch -------------
__global__ void outcomb2_kernel(const float* __restrict__ regmu, const float* __restrict__ regsg,
                                const float* __restrict__ gA, const float* __restrict__ gA2,
                                const float* __restrict__ gB, const float* __restrict__ gB2,
                                float* __restrict__ out) {
    int i = blockIdx.x * blockDim.x + threadIdx.x;
    if (i >= NBT) return;
    int nb = i / DD;
    if (blockIdx.y == 0) out[i]       = (regmu[nb] + gA[i] + gA2[i]) * (1.0f / 3.0f);
    else                 out[NBT + i] = (regsg[nb] + gB[i] + gB2[i]) * (1.0f / 3.0f);
}

extern "C" void kernel_launch(void* const* d_in, const int* in_sizes, int n_in,
                              void* d_out, int out_size, void* d_ws, size_t ws_size,
                              hipStream_t stream) {
    const float* x      = (const float*)d_in[0];
    const int* ps_src   = (const int*)d_in[1];
    const int* ps_dst   = (const int*)d_in[2];
    const int* rl_src   = (const int*)d_in[3];
    const int* rl_dst   = (const int*)d_in[4];
    const float* mu_p_fc = (const float*)d_in[5];
    const float* mu_p_al = (const float*)d_in[6];
    const float* mu_p_ar = (const float*)d_in[7];
    const float* sg_p_fc = (const float*)d_in[8];
    const float* sg_p_al = (const float*)d_in[9];
    const float* sg_p_ar = (const float*)d_in[10];
    const float* mu_r_fc = (const float*)d_in[11];
    const float* mu_r_al = (const float*)d_in[12];
    const float* mu_r_ar = (const float*)d_in[13];
    const float* sg_r_fc = (const float*)d_in[14];
    const float* sg_r_al = (const float*)d_in[15];
    const float* sg_r_ar = (const float*)d_in[16];
    const float* reg_mu_w = (const float*)d_in[17];
    const float* reg_mu_b = (const float*)d_in[18];
    const float* reg_sg_w = (const float*)d_in[19];
    const float* reg_sg_b = (const float*)d_in[20];

    float* out = (float*)d_out;

    // ---- workspace carve ----
    float* fw = (float*)d_ws;
    float* ms    = fw;              fw += NBM;   // interleaved mu|sigma, stride 24
    float* hp    = fw;              fw += NBF;   // stride-12 feats
    float* hrl   = fw;              fw += NBF;
    float* gA    = fw;              fw += NBT;   // stride-10 GAT outputs
    float* gB    = fw;              fw += NBT;
    float* gA2   = fw;              fw += NBT;
    float* gB2   = fw;              fw += NBT;
    float* regmu = fw;              fw += NB;
    float* regsg = fw;              fw += NB;
    float* vbuf  = fw;              fw += 8 * 80;
    int* iw = (int*)fw;
    int* ps_off = iw;               iw += NN + 1;
    int* rl_off = iw;               iw += NN + 1;
    int* ps_csr = iw;               iw += EE;
    int* rl_csr = iw;               iw += EE;
    int* perm_ps = iw;              iw += NN;
    int* perm_rl = iw;              iw += NN;
    int* boff   = iw;               iw += 128;
    // zero region starts here:
    int* deg_ps = iw;               iw += NN;
    int* cur_ps = iw;               iw += NN;
    int* deg_rl = iw;               iw += NN;
    int* cur_rl = iw;               iw += NN;
    int* hist   = iw;               iw += 128;
    int* bcur   = iw;               iw += 128;
    float* stats = (float*)iw;      // 8 floats
    size_t zero_bytes = (size_t)(4 * NN + 256) * sizeof(int) + 8 * sizeof(float);
    hipMemsetAsync(deg_ps, 0, zero_bytes, stream);

    const int TPB = 256;
    const int GRID_NB  = (NB + TPB - 1) / TPB;      // 1250
    const int GRID_NBT = (NBT + TPB - 1) / TPB;
    const int GRID_E   = (EE + TPB - 1) / TPB;
    const int GRID_N   = (NN + TPB - 1) / TPB;      // 40

    extract_kernel<<<GRID_NB, TPB, 0, stream>>>(x, reg_mu_w, reg_mu_b, reg_sg_w, reg_sg_b,
                                                ms, regmu, regsg);

    // CSR + degree-sort for both graphs (fused dispatches)
    {
        dim3 g(GRID_E, 2, 1);
        dim3 gn(GRID_N, 2, 1);
        deg2_kernel<<<g, TPB, 0, stream>>>(ps_dst, deg_ps, rl_dst, deg_rl);
        scan2_kernel<<<2, 1024, 0, stream>>>(deg_ps, ps_off, deg_rl, rl_off);
        fill2_kernel<<<g, TPB, 0, stream>>>(ps_src, ps_dst, ps_off, cur_ps, ps_csr,
                                            rl_src, rl_dst, rl_off, cur_rl, rl_csr);
        hist2_kernel<<<gn, TPB, 0, stream>>>(deg_ps, deg_rl, hist);
        binoff_kernel<<<1, 128, 0, stream>>>(hist, boff);
        permfill2_kernel<<<gn, TPB, 0, stream>>>(deg_ps, deg_rl, boff, bcur, perm_ps, perm_rl);
    }

    // vl/vr precompute for all 8 GAT slots
    vpre_kernel<<<1, 320, 0, stream>>>(mu_p_fc, mu_p_al, mu_p_ar,
                                       sg_p_fc, sg_p_al, sg_p_ar,
                                       mu_r_fc, mu_r_al, mu_r_ar,
                                       sg_r_fc, sg_r_al, sg_r_ar, vbuf);

    // slots: 0 mu_p L0, 1 sg_p L0, 2 mu_r L0, 3 sg_r L0, 4 mu_p L1, 5 sg_p L1, 6 mu_r L1, 7 sg_r L1
    // ---- layer 0: 2 pairs (ps: mu_p+sg_p, rl: mu_r+sg_r) on interleaved ms ----
    {
        PairCfg2 c;
        c.c[0] = { ms, mu_p_fc, sg_p_fc, vbuf + 0 * 80, vbuf + 1 * 80,
                   ps_off, ps_csr, perm_ps, gA,  gB,  stats + 0, stats + 2 };
        c.c[1] = { ms, mu_r_fc, sg_r_fc, vbuf + 2 * 80, vbuf + 3 * 80,
                   rl_off, rl_csr, perm_rl, gA2, gB2, stats + 4, stats + 6 };
        dim3 grid(GRID_NB, 2, 1);
        gatpair_kernel<true, true><<<grid, TPB, 0, stream>>>(c);
    }
    {
        dim3 g(GRID_NBT, 2, 1);
        lncomb2_kernel<<<g, TPB, 0, stream>>>(gA, gB, gA2, gB2, stats, hp, hrl);
    }

    // ---- final layers: 2 pairs, shared feature row per pair ----
    {
        PairCfg2 c;
        c.c[0] = { hp,  mu_p_fc + 400, sg_p_fc + 400, vbuf + 4 * 80, vbuf + 5 * 80,
                   ps_off, ps_csr, perm_ps, gA,  gB,  nullptr, nullptr };
        c.c[1] = { hrl, mu_r_fc + 400, sg_r_fc + 400, vbuf + 6 * 80, vbuf + 7 * 80,
                   rl_off, rl_csr, perm_rl, gA2, gB2, nullptr, nullptr };
        dim3 grid(GRID_NB, 2, 1);
        gatpair_kernel<false, false><<<grid, TPB, 0, stream>>>(c);
    }

    {
        dim3 g(GRID_NBT, 2, 1);
        outcomb2_kernel<<<g, TPB, 0, stream>>>(regmu, regsg, gA, gA2, gB, gB2, out);
    }
}